// Round 14
// baseline (17632.794 us; speedup 1.0000x reference)
//
#include <hip/hip_runtime.h>
#include <hip/hip_cooperative_groups.h>
#include <math.h>

constexpr int T = 4096;   // SEQ_LEN
constexpr int R = 2048;   // RES_SIZE
constexpr int J = 128;    // INPUT_SIZE
constexpr float ONE_MINUS_LEAK = 0.1f;
constexpr float LEAK = 0.9f;
constexpr float INV_SQRT_R = 0.022097086912079608f;  // 1/sqrt(2048)

constexpr int NWG  = 64;   // 512-thread WGs; 512 waves total
constexpr int NREP = 2;    // slot replicas (R5/R11 sweet spot)

// ---------------- Kernel A: proj[t][r] = input[t] . W_in[r] + bias[r] -> d_out
__global__ __launch_bounds__(256) void esn_proj_kernel(
    const float* __restrict__ U, const float* __restrict__ Win,
    const float* __restrict__ bias, float* __restrict__ out)
{
    __shared__ float As[16][129];
    __shared__ float Bs[16][129];
    const int tb = blockIdx.x * 16;
    const int rb = blockIdx.y * 16;
    const int tid = threadIdx.x;

    for (int i = tid; i < 16 * J; i += 256) {
        int r = i >> 7, c = i & 127;
        As[r][c] = U[(size_t)(tb + r) * J + c];
        Bs[r][c] = Win[(size_t)(rb + r) * J + c];
    }
    __syncthreads();

    const int ti = tid >> 4;
    const int rj = tid & 15;
    float acc = 0.f;
#pragma unroll
    for (int k = 0; k < J; ++k) acc = fmaf(As[ti][k], Bs[rj][k], acc);
    out[(size_t)(tb + ti) * R + (rb + rj)] = acc + bias[rb + rj];
}

// ---------------- Kernel B: barrier-free recurrence, poll-into-registers.
// 64 WGs x 512 threads; wave (wg,v) owns rows rowbase=32wg+4v..+3.
// slots[2][NREP][R] u32: bits[31:8] = f32 value (low mantissa byte stolen,
// ~3e-7 quantization -- R13-proven), bits[7:0] = tag (t & 0xFF).
// Each thread polls EXACTLY the 32 slots its dot needs (x[k*64+lane]) with
// 32 dword loads in flight under one vmcnt(0); on sweep exit the fresh
// values are already in the FMA input registers. No LDS, no __syncthreads,
// no 512-thread detect join. Skew<=1 induction (per-wave): tag t+2 reaches
// buffer t&1 only after all waves published t+1, which requires every
// wave's detect(t) to have exited. Live tags differ by <=2 -> 8-bit tag ok.
__global__ __launch_bounds__(512) void esn_recur_kernel(
    const float* __restrict__ Wres, float* __restrict__ out,
    unsigned* __restrict__ slots /* [2][NREP][R] */)
{
    const int wg   = blockIdx.x;
    const int tid  = threadIdx.x;
    const int wv   = tid >> 6;
    const int lane = tid & 63;
    const int rowbase = wg * 32 + wv * 4;   // this wave's 4 rows
    const int rep  = wg & (NREP - 1);

    // 4 rows of weights in registers (coalesced: 64 lanes x f32 per k).
    float w[4][32];
#pragma unroll
    for (int j = 0; j < 4; ++j) {
        const float* wr = Wres + (size_t)(rowbase + j) * R + lane;
#pragma unroll
        for (int k = 0; k < 32; ++k) w[j][k] = wr[k * 64];
    }

    float xold = 0.f;    // lanes 0..3: previous state of row rowbase+lane
    long  spin = 0;      // cumulative guard: bugs -> fast wrong answer

    for (int t = 0; t < T; ++t) {
        // Input projection prefetch (latency hides under the poll).
        float proj = (lane < 4) ? out[(size_t)t * R + rowbase + lane] : 0.f;

        // ---- Poll my 32 dot operands: x[k*64+lane], k=0..31.
        const unsigned* base =
            slots + ((size_t)((t & 1) * NREP + rep)) * R + lane;
        const unsigned* p0 = base;          // k=0..15  (offsets 0..3840)
        const unsigned* p1 = base + 1024;   // k=16..31 (offsets 0..3840)
        const unsigned want = (unsigned)t & 0xFFu;
        unsigned v[32];
        while (true) {
            asm volatile(
                "global_load_dword %0,  %32, off sc0 sc1\n\t"
                "global_load_dword %1,  %32, off offset:256 sc0 sc1\n\t"
                "global_load_dword %2,  %32, off offset:512 sc0 sc1\n\t"
                "global_load_dword %3,  %32, off offset:768 sc0 sc1\n\t"
                "global_load_dword %4,  %32, off offset:1024 sc0 sc1\n\t"
                "global_load_dword %5,  %32, off offset:1280 sc0 sc1\n\t"
                "global_load_dword %6,  %32, off offset:1536 sc0 sc1\n\t"
                "global_load_dword %7,  %32, off offset:1792 sc0 sc1\n\t"
                "global_load_dword %8,  %32, off offset:2048 sc0 sc1\n\t"
                "global_load_dword %9,  %32, off offset:2304 sc0 sc1\n\t"
                "global_load_dword %10, %32, off offset:2560 sc0 sc1\n\t"
                "global_load_dword %11, %32, off offset:2816 sc0 sc1\n\t"
                "global_load_dword %12, %32, off offset:3072 sc0 sc1\n\t"
                "global_load_dword %13, %32, off offset:3328 sc0 sc1\n\t"
                "global_load_dword %14, %32, off offset:3584 sc0 sc1\n\t"
                "global_load_dword %15, %32, off offset:3840 sc0 sc1\n\t"
                "global_load_dword %16, %33, off sc0 sc1\n\t"
                "global_load_dword %17, %33, off offset:256 sc0 sc1\n\t"
                "global_load_dword %18, %33, off offset:512 sc0 sc1\n\t"
                "global_load_dword %19, %33, off offset:768 sc0 sc1\n\t"
                "global_load_dword %20, %33, off offset:1024 sc0 sc1\n\t"
                "global_load_dword %21, %33, off offset:1280 sc0 sc1\n\t"
                "global_load_dword %22, %33, off offset:1536 sc0 sc1\n\t"
                "global_load_dword %23, %33, off offset:1792 sc0 sc1\n\t"
                "global_load_dword %24, %33, off offset:2048 sc0 sc1\n\t"
                "global_load_dword %25, %33, off offset:2304 sc0 sc1\n\t"
                "global_load_dword %26, %33, off offset:2560 sc0 sc1\n\t"
                "global_load_dword %27, %33, off offset:2816 sc0 sc1\n\t"
                "global_load_dword %28, %33, off offset:3072 sc0 sc1\n\t"
                "global_load_dword %29, %33, off offset:3328 sc0 sc1\n\t"
                "global_load_dword %30, %33, off offset:3584 sc0 sc1\n\t"
                "global_load_dword %31, %33, off offset:3840 sc0 sc1\n\t"
                "s_waitcnt vmcnt(0)"
                : "=&v"(v[0]),  "=&v"(v[1]),  "=&v"(v[2]),  "=&v"(v[3]),
                  "=&v"(v[4]),  "=&v"(v[5]),  "=&v"(v[6]),  "=&v"(v[7]),
                  "=&v"(v[8]),  "=&v"(v[9]),  "=&v"(v[10]), "=&v"(v[11]),
                  "=&v"(v[12]), "=&v"(v[13]), "=&v"(v[14]), "=&v"(v[15]),
                  "=&v"(v[16]), "=&v"(v[17]), "=&v"(v[18]), "=&v"(v[19]),
                  "=&v"(v[20]), "=&v"(v[21]), "=&v"(v[22]), "=&v"(v[23]),
                  "=&v"(v[24]), "=&v"(v[25]), "=&v"(v[26]), "=&v"(v[27]),
                  "=&v"(v[28]), "=&v"(v[29]), "=&v"(v[30]), "=&v"(v[31])
                : "v"(p0), "v"(p1)
                : "memory");
            bool ok = true;
#pragma unroll
            for (int k = 0; k < 32; ++k) ok &= ((v[k] & 0xFFu) == want);
            if (ok) break;
            if (++spin > (1L << 26)) break;
        }
        // Strip tags in place; values feed the FMAs directly.
#pragma unroll
        for (int k = 0; k < 32; ++k) v[k] &= 0xFFFFFF00u;

        // ---- 4-row dot on in-register x, wave shuffle reduce.
        float mysum = 0.f;
#pragma unroll
        for (int j = 0; j < 4; ++j) {
            float a0 = 0.f, a1 = 0.f, a2 = 0.f, a3 = 0.f;
#pragma unroll
            for (int k = 0; k < 8; ++k) {
                a0 = fmaf(w[j][4 * k + 0], __uint_as_float(v[4 * k + 0]), a0);
                a1 = fmaf(w[j][4 * k + 1], __uint_as_float(v[4 * k + 1]), a1);
                a2 = fmaf(w[j][4 * k + 2], __uint_as_float(v[4 * k + 2]), a2);
                a3 = fmaf(w[j][4 * k + 3], __uint_as_float(v[4 * k + 3]), a3);
            }
            float acc = (a0 + a1) + (a2 + a3);
#pragma unroll
            for (int off = 32; off > 0; off >>= 1)
                acc += __shfl_xor(acc, off);
            if (lane == j) mysum = acc;          // static j -> cndmask
        }

        // ---- Lanes 0..3 finalize their row, publish, write output.
        if (lane < 4) {
            const float pre  = mysum + proj;     // proj includes bias
            const float xnew = ONE_MINUS_LEAK * xold +
                               LEAK * erff(pre) * INV_SQRT_R;
            xold = xnew;
            // Pack: round-to-nearest on the stolen byte, then insert tag.
            const unsigned bits =
                ((__float_as_uint(xnew) + 0x80u) & 0xFFFFFF00u) |
                ((unsigned)(t + 1) & 0xFFu);
            const size_t pb = (size_t)(((t + 1) & 1) * NREP) * R
                            + rowbase + lane;
#pragma unroll
            for (int g = 0; g < NREP; ++g)
                __hip_atomic_store(&slots[pb + (size_t)g * R], bits,
                                   __ATOMIC_RELAXED, __HIP_MEMORY_SCOPE_AGENT);
            out[(size_t)t * R + rowbase + lane] = xnew;  // states output
        }
    }
}

extern "C" void kernel_launch(void* const* d_in, const int* in_sizes, int n_in,
                              void* d_out, int out_size, void* d_ws, size_t ws_size,
                              hipStream_t stream) {
    const float* U    = (const float*)d_in[0];  // (4096,128)
    const float* Win  = (const float*)d_in[1];  // (2048,128)
    const float* Wres = (const float*)d_in[2];  // (2048,2048)
    const float* bias = (const float*)d_in[3];  // (2048,)
    float* out = (float*)d_out;                 // (4096,2048)
    unsigned* slots = (unsigned*)d_ws;          // [2][NREP][R] u32

    // All-zero slots: tag 0 == (t=0)&0xFF, value bits 0 == x^0 = 0. Valid.
    hipMemsetAsync(slots, 0, (size_t)2 * NREP * R * sizeof(unsigned), stream);

    dim3 pgrid(T / 16, R / 16);
    esn_proj_kernel<<<pgrid, dim3(256), 0, stream>>>(U, Win, bias, out);

    void* args[] = { (void*)&Wres, (void*)&out, (void*)&slots };
    hipLaunchCooperativeKernel((const void*)esn_recur_kernel,
                               dim3(NWG), dim3(512), args, 0, stream);
}